// Round 11
// baseline (211.491 us; speedup 1.0000x reference)
//
#include <hip/hip_runtime.h>
#include <math.h>

// Capsule dynamic routing, MI355X. Round 11: transpose-u for coalesced
// phase-1 + R5-proven route structure + last-block squash fusion. 5 dispatches.
//   logits[b,j,n] = u[b,n,:] . V[b,j,:],  V[b,j,k] = sum_d W[k,jd]*o[b,j,d]
//   o[b,j,d]      = sum_k G[b,j,k]*W[k,jd], G[b,j,k] = sum_n c[b,j,n]*u[b,n,k]
// iter0: c uniform 0.1 -> o0 = 0.1*(colsum u)@W.
// HARD-WON RULES:
//  - Phase-1 V reads MUST be wave-uniform through a const __restrict__
//    pointer the kernel never writes -> s_load path (R7/R8: ~2.5x if broken).
//  - All-fp32 math (R6: bf16 u fails the 2% threshold).
//  - R10 counters: phase-1 thread=row reads were 64 cache lines/wave-load ->
//    latency-bound at 12% occupancy. R11: read uT[k][n] (lanes along n).

#define BATCH 64
#define NN    2048
#define KD    128
#define JCAP  10
#define DCAP  16
#define JDIM  160
#define EPSQ  1e-7f
#define TPB   256

// ws layout (float offsets):
//  Sp  [64][32][128]    @ 0        (262144)
//  Gp1 [64][8][1280]    @ 262144   (655360)
//  O2p [64][8][160]     @ 917504   (81920)
//  V0  [64][10][128]    @ 999424   (81920)
//  V1  [64][10][128]    @ 1081344  (81920)
//  cnt [64] uint        @ 1163264  (64)
//  uT  [64][128][2048]  @ 1163328  (16777216)   total ~71.8 MB
#define WS_SP   0
#define WS_GP1  262144
#define WS_O2P  917504
#define WS_V0   999424
#define WS_V1   1081344
#define WS_CNT  1163264
#define WS_UT   1163328

// ---- K1: transpose u -> uT[b][k][n] + colsum partials + zero counters ----
// grid (32, 64): 64-row tiles. Read coalesced, LDS-staged, write ~coalesced.
__global__ __launch_bounds__(TPB) void k_tpose(const float* __restrict__ u,
                                               float* __restrict__ uT,
                                               float* __restrict__ Sp,
                                               unsigned int* __restrict__ cnt) {
  const int b = blockIdx.y, tile = blockIdx.x, t = threadIdx.x;
  if (b == 0 && tile == 0 && t < BATCH) cnt[t] = 0u;
  __shared__ __align__(16) float Ts[64][132];   // +4 pad: b128-aligned rows
  __shared__ float4 red[256];
  const float* src = u + ((size_t)b * NN + tile * 64) * KD;
  float4 csum = make_float4(0.f, 0.f, 0.f, 0.f);
#pragma unroll
  for (int q = 0; q < 8; ++q) {
    const int idx = t + 256 * q;          // 2048 float4 of the 64x128 tile
    const int row = idx >> 5, k4 = idx & 31;
    float4 w = *(const float4*)(src + (size_t)row * KD + k4 * 4);
    csum.x += w.x; csum.y += w.y; csum.z += w.z; csum.w += w.w;
    *(float4*)&Ts[row][k4 * 4] = w;
  }
  red[t] = csum;                           // thread t covers rows (t>>5)+8q, k4=t&31
  __syncthreads();
  if (t < 32) {                            // fold 8 row-groups per k4
    float4 s4 = red[t];
#pragma unroll
    for (int g = 1; g < 8; ++g) {
      float4 w = red[t + 32 * g];
      s4.x += w.x; s4.y += w.y; s4.z += w.z; s4.w += w.w;
    }
    *(float4*)&Sp[(size_t)(b * 32 + tile) * KD + t * 4] = s4;
  }
  // transposed write: uT[b][k][tile*64 + n]
  float* dstb = uT + (size_t)b * (NN * KD) + tile * 64;
#pragma unroll
  for (int q = 0; q < 8; ++q) {
    const int idx = t + 256 * q;          // 128 k x 16 float4-of-n
    const int k = idx >> 4, n4 = idx & 15;
    float4 v = make_float4(Ts[n4 * 4 + 0][k], Ts[n4 * 4 + 1][k],
                           Ts[n4 * 4 + 2][k], Ts[n4 * 4 + 3][k]);
    *(float4*)(dstb + (size_t)k * NN + n4 * 4) = v;
  }
}

// ---- K2/K4: fold partials -> o = Gsum@W -> V (global) ------------------
__global__ __launch_bounds__(TPB) void k_makeV(const float* __restrict__ ws,
                                               const float* __restrict__ W,
                                               float* __restrict__ V,
                                               int pass) {
  const int b = blockIdx.x, t = threadIdx.x;
  __shared__ float gsum[JCAP * KD];   // pass0 uses first 128 only
  __shared__ float o_s[JDIM];
  if (pass == 0) {
    const float* SpB = ws + WS_SP + (size_t)b * 32 * KD;
    if (t < KD) {
      float s = 0.f;
#pragma unroll
      for (int tl = 0; tl < 32; ++tl) s += SpB[tl * KD + t];
      gsum[t] = s * 0.1f;
    }
  } else {
    const float* GpB = ws + WS_GP1 + (size_t)b * 8 * (JCAP * KD);
    for (int i = t; i < JCAP * KD; i += TPB) {
      float s = 0.f;
#pragma unroll
      for (int tl = 0; tl < 8; ++tl) s += GpB[(size_t)tl * (JCAP * KD) + i];
      gsum[i] = s;
    }
  }
  __syncthreads();
  if (t < JDIM) {
    const int j = t >> 4;
    const float* gs = pass == 0 ? gsum : (gsum + j * KD);
    float acc = 0.f;
#pragma unroll 4
    for (int k = 0; k < KD; ++k) acc += gs[k] * W[k * JDIM + t];
    o_s[t] = acc;
  }
  __syncthreads();
  const int k = t & 127, gg = t >> 7;
#pragma unroll
  for (int i = 0; i < 5; ++i) {
    const int j = gg * 5 + i;
    const float* wp = W + k * JDIM + j * DCAP;
    float acc = 0.f;
#pragma unroll
    for (int d = 0; d < DCAP; ++d) acc += wp[d] * o_s[j * DCAP + d];
    V[(size_t)(b * JCAP + j) * KD + k] = acc;
  }
}

// ---- K3/K5: route pass. 256-row tiles, 512 blocks ----------------------
// phase 1 reads uT (coalesced along n); phase 2 reads row-major u.
// pass0: dst = Gp1 partials [b][tile][1280]
// pass1: dst = O2p partials [b][tile][160]; last block/batch squashes.
__global__ __launch_bounds__(TPB) void k_route(const float* __restrict__ u,
                                               const float* __restrict__ uT,
                                               const float* __restrict__ V,
                                               const float* __restrict__ W,
                                               float* __restrict__ dst,
                                               float* __restrict__ out,
                                               unsigned int* __restrict__ cnt,
                                               int pass) {
  const int b = blockIdx.y, tile = blockIdx.x, t = threadIdx.x;
  const int r0 = tile * 256;
  __shared__ __align__(16) float Cs[JCAP][260];
  __shared__ __align__(16) float Gp[4][JCAP][KD];
  __shared__ float o_s[JDIM];
  __shared__ float sc[JCAP];
  __shared__ unsigned int lastflag;

  // phase 1: thread = row n; u via uT (lanes consecutive in n -> coalesced);
  // V reads wave-uniform -> s_loads (NEVER break this).
  {
    const float* uTb = uT + (size_t)b * (NN * KD) + r0 + t;   // [k][n], n fixed
    const float* vb = V + (size_t)(b * JCAP) * KD;
    float acc[JCAP];
#pragma unroll
    for (int j = 0; j < JCAP; ++j) acc[j] = 0.f;
    for (int k = 0; k < KD; k += 8) {
      float x0 = uTb[(size_t)(k + 0) * NN];
      float x1 = uTb[(size_t)(k + 1) * NN];
      float x2 = uTb[(size_t)(k + 2) * NN];
      float x3 = uTb[(size_t)(k + 3) * NN];
      float x4 = uTb[(size_t)(k + 4) * NN];
      float x5 = uTb[(size_t)(k + 5) * NN];
      float x6 = uTb[(size_t)(k + 6) * NN];
      float x7 = uTb[(size_t)(k + 7) * NN];
#pragma unroll
      for (int j = 0; j < JCAP; ++j) {
        const float* vj = vb + j * KD + k;
        acc[j] += x0 * vj[0] + x1 * vj[1] + x2 * vj[2] + x3 * vj[3]
                + x4 * vj[4] + x5 * vj[5] + x6 * vj[6] + x7 * vj[7];
      }
    }
    float m = acc[0];
#pragma unroll
    for (int j = 1; j < JCAP; ++j) m = fmaxf(m, acc[j]);
    float s = 0.f;
#pragma unroll
    for (int j = 0; j < JCAP; ++j) { acc[j] = __expf(acc[j] - m); s += acc[j]; }
    const float inv = 1.f / s;
#pragma unroll
    for (int j = 0; j < JCAP; ++j) Cs[j][t] = acc[j] * inv;
  }
  __syncthreads();

  // phase 2: wave = 64 rows, lane = k-pair (coalesced row-major u reads)
  {
    const int wave = t >> 6, lane = t & 63;
    const int rw = wave * 64;
    float g0[JCAP], g1[JCAP];
#pragma unroll
    for (int j = 0; j < JCAP; ++j) { g0[j] = 0.f; g1[j] = 0.f; }
    const float* ub = u + (size_t)(b * NN + r0 + rw) * KD + 2 * lane;
    for (int rc = 0; rc < 64; rc += 4) {
      float ua[4], uc[4];
#pragma unroll
      for (int q = 0; q < 4; ++q) {
        float2 w = *(const float2*)(ub + (size_t)(rc + q) * KD);
        ua[q] = w.x; uc[q] = w.y;
      }
#pragma unroll
      for (int j = 0; j < JCAP; ++j) {
        float4 c4 = *(const float4*)&Cs[j][rw + rc];
        g0[j] += c4.x * ua[0] + c4.y * ua[1] + c4.z * ua[2] + c4.w * ua[3];
        g1[j] += c4.x * uc[0] + c4.y * uc[1] + c4.z * uc[2] + c4.w * uc[3];
      }
    }
#pragma unroll
    for (int j = 0; j < JCAP; ++j)
      *(float2*)&Gp[wave][j][2 * lane] = make_float2(g0[j], g1[j]);
  }
  __syncthreads();

  if (pass == 0) {
    float* g1d = dst + (size_t)(b * 8 + tile) * (JCAP * KD);
    for (int i = t; i < JCAP * KD; i += TPB)
      g1d[i] = Gp[0][0][i] + Gp[1][0][i] + Gp[2][0][i] + Gp[3][0][i];
    return;
  }

  // pass 1 tail: O2 partial -> counter -> last block squashes
  for (int i = t; i < JCAP * KD; i += TPB)
    Gp[0][0][i] = Gp[0][0][i] + Gp[1][0][i] + Gp[2][0][i] + Gp[3][0][i];
  __syncthreads();
  if (t < JDIM) {
    const int j = t >> 4;
    float acc = 0.f;
#pragma unroll 4
    for (int k = 0; k < KD; ++k) acc += Gp[0][j][k] * W[k * JDIM + t];
    dst[(size_t)(b * 8 + tile) * JDIM + t] = acc;
  }
  __syncthreads();
  if (t == 0) {
    __threadfence();                       // publish O2 partial
    lastflag = atomicAdd(&cnt[b], 1u);     // 7 => we are the last block
  }
  __syncthreads();
  if (lastflag != 7u) return;
  __threadfence();                         // acquire others' partials

  const float* p = dst + (size_t)b * 8 * JDIM;
  if (t < JDIM) {
    float s = 0.f;
#pragma unroll
    for (int tl = 0; tl < 8; ++tl) s += p[tl * JDIM + t];
    o_s[t] = s;
  }
  __syncthreads();
  if (t < JCAP) {
    float s2 = 0.f;
#pragma unroll
    for (int d = 0; d < DCAP; ++d) { float x = o_s[t * DCAP + d]; s2 += x * x; }
    sc[t] = s2 / ((1.f + s2) * sqrtf(s2 + EPSQ));
  }
  __syncthreads();
  if (t < JDIM) out[b * JDIM + t] = o_s[t] * sc[t >> 4];
}

extern "C" void kernel_launch(void* const* d_in, const int* in_sizes, int n_in,
                              void* d_out, int out_size, void* d_ws, size_t ws_size,
                              hipStream_t stream) {
  const float* u = (const float*)d_in[0];   // (64,2048,128) fp32
  const float* W = (const float*)d_in[1];   // (128,160) fp32
  float* out = (float*)d_out;               // (64,10,16) fp32
  float* ws  = (float*)d_ws;

  float* Sp  = ws + WS_SP;
  float* Gp1 = ws + WS_GP1;
  float* O2p = ws + WS_O2P;
  float* V0  = ws + WS_V0;
  float* V1  = ws + WS_V1;
  float* uT  = ws + WS_UT;
  unsigned int* cnt = (unsigned int*)(ws + WS_CNT);

  k_tpose<<<dim3(32, BATCH), TPB, 0, stream>>>(u, uT, Sp, cnt);
  k_makeV<<<BATCH, TPB, 0, stream>>>(ws, W, V0, 0);
  k_route<<<dim3(8, BATCH), TPB, 0, stream>>>(u, uT, V0, W, Gp1, out, cnt, 0);
  k_makeV<<<BATCH, TPB, 0, stream>>>(ws, W, V1, 1);
  k_route<<<dim3(8, BATCH), TPB, 0, stream>>>(u, uT, V1, W, O2p, out, cnt, 1);
}